// Round 6
// baseline (262.074 us; speedup 1.0000x reference)
//
#include <hip/hip_runtime.h>
#include <hip/hip_bf16.h>

// Problem constants (from reference)
#define MA 60000
#define PA 20
#define CA 5
#define MR 80000
#define PR 32
#define CR 3
#define NXg 256
#define NYg 256
#define NB 8
#define NCELL (NB * NYg * NXg)   // 524288

typedef __bf16 bf16x8 __attribute__((ext_vector_type(8)));
typedef float  f32x4  __attribute__((ext_vector_type(4)));
typedef float  f4     __attribute__((ext_vector_type(4)));

__device__ __forceinline__ unsigned short f2bf(float f) {
    unsigned int u = __float_as_uint(f);
    u += 0x7fffu + ((u >> 16) & 1u);   // round-to-nearest-even
    return (unsigned short)(u >> 16);
}

// ---------------------------------------------------------------------------
// prep: conv-weight B-fragment pack only (win init via hipMemsetAsync).
// Pack order: offset = tap*4096 + kk*1024 + nt*512 + lane*8 + j,
// with n = nt*16+(lane&15), k = kk*32+(lane>>4)*8+j.
__global__ void __launch_bounds__(256) prep_kernel(const float* __restrict__ conv_w,
                                                   unsigned short* __restrict__ bp) {
    int i = blockIdx.x * 256 + threadIdx.x;    // < 144*256 = 36864 exactly
    int j    = i & 7;
    int lane = (i >> 3) & 63;
    int nt   = (i >> 9) & 1;
    int kk   = (i >> 10) & 3;
    int tap  = i >> 12;
    int n = nt * 16 + (lane & 15);
    int k = kk * 32 + (lane >> 4) * 8 + j;
    bp[i] = f2bf(conv_w[(tap * 128 + k) * 32 + n]);
}

// ---------------------------------------------------------------------------
// Pillar VFE v11: ZERO-LDS wave-broadcast design.
// Each wave owns 16 pillars. Point data is loaded at WAVE-UNIFORM global
// addresses (contiguous per pillar) -> compiler scalarizes to s_load, point
// values live in SGPRs and broadcast into per-lane FMAs against the lane's
// weight column. No LDS, no staging, no transpose, no barriers, no dup-fill.
// Sums/max iterate only VALID points: full 4-point groups unguarded, the
// tail group uses uniform (j < rem) guards -> exact, no corrections.
#define EL(K) q[(K) >> 2][(K) & 3]

template <int CIN, int CF, int PMAX>
__device__ __forceinline__ void vfe_wave(
    int wpid, const float* __restrict__ vox, const int* __restrict__ coors,
    const int* __restrict__ npts, const float* __restrict__ W,
    const float* __restrict__ bias, unsigned short* __restrict__ feat,
    int* __restrict__ win, int which)
{
    constexpr int PC4 = PMAX * CIN / 4;    // f4s per pillar (25 agent, 24 rg)

    int lane = threadIdx.x & 63;
    int base = wpid * 16;                  // 16 pillars per wave, exact fit

    // per-lane weight column + folded weights
    float wc[CF];
#pragma unroll
    for (int c = 0; c < CF; ++c) wc[c] = W[c * 64 + lane];
    float bd = bias[lane];
    float w0 = wc[0] + wc[CIN + 0] + wc[CIN + 3];
    float w1 = wc[1] + wc[CIN + 1] + wc[CIN + 4];
    float w2 = wc[2] + wc[CIN + 2];

    for (int pi = 0; pi < 16; ++pi) {
        int gid = base + pi;
        int np = npts[gid];
        np = np < 1 ? 1 : (np > PMAX ? PMAX : np);
        int nb  = (np + 3) >> 2;
        int rem = np - (nb - 1) * 4;       // 1..4 valid points in tail group
        const f4* gp = (const f4*)vox + (size_t)gid * PC4;
        int cb = coors[gid * 3 + 0];
        int cy = coors[gid * 3 + 1];
        int cx = coors[gid * 3 + 2];

        float b = -1e30f, sx = 0.f, sy = 0.f, sz = 0.f;

        // full groups (4 valid points each) — no guards
        int g = 0;
        for (; g + 1 < nb; ++g) {
            f4 q[CIN];
#pragma unroll
            for (int t = 0; t < CIN; ++t) q[t] = gp[g * CIN + t];
#pragma unroll
            for (int j = 0; j < 4; ++j) {
                float x = EL(j * CIN + 0);
                float y = EL(j * CIN + 1);
                float z = EL(j * CIN + 2);
                float d = x * w0 + y * w1 + z * w2;
#pragma unroll
                for (int c = 3; c < CIN; ++c) d += EL(j * CIN + c) * wc[c];
                b = fmaxf(b, d);
                sx += x; sy += y; sz += z;
            }
        }
        // tail group — uniform (j < rem) guards, only valid points touched
        {
            f4 q[CIN];
#pragma unroll
            for (int t = 0; t < CIN; ++t) q[t] = gp[g * CIN + t];
#pragma unroll
            for (int j = 0; j < 4; ++j) {
                if (j < rem) {
                    float x = EL(j * CIN + 0);
                    float y = EL(j * CIN + 1);
                    float z = EL(j * CIN + 2);
                    float d = x * w0 + y * w1 + z * w2;
#pragma unroll
                    for (int c = 3; c < CIN; ++c) d += EL(j * CIN + c) * wc[c];
                    b = fmaxf(b, d);
                    sx += x; sy += y; sz += z;
                }
            }
        }

        float inv = 1.0f / (float)np;
        float mx = sx * inv, my = sy * inv, mz = sz * inv;
        float xo = (float)cx * 0.3125f + (-39.84375f);   // VX, X_OFF exact
        float yo = (float)cy * 0.3125f + (-19.84375f);
        float off = bd - (mx * wc[CIN + 0] + my * wc[CIN + 1] + mz * wc[CIN + 2])
                       - xo * wc[CIN + 3] - yo * wc[CIN + 4];
        float best = fmaxf(0.0f, b + off);

        feat[(size_t)gid * 64 + lane] = f2bf(best);

        if (lane == 0) {
            // numpy last-write-wins == max pillar index wins; int2 map
            atomicMax(&win[((cb * NYg + cy) * NXg + cx) * 2 + which], gid);
        }
    }
}

// Unified VFE launch: 8750 waves (3750 agent + 5000 rg), 4 waves/block,
// interleaved 3:4 (3750:5000 = 3:4 exactly). No LDS, no barriers ->
// occupancy limited only by VGPR (target <=64 -> 8 waves/SIMD).
__global__ void __launch_bounds__(256, 8) vfe_all(
    const float* __restrict__ vox_a, const int* __restrict__ coor_a,
    const int* __restrict__ np_a, const float* __restrict__ w_a,
    const float* __restrict__ b_a, unsigned short* __restrict__ feat_a,
    const float* __restrict__ vox_r, const int* __restrict__ coor_r,
    const int* __restrict__ np_r, const float* __restrict__ w_r,
    const float* __restrict__ b_r, unsigned short* __restrict__ feat_r,
    int* __restrict__ win)
{
    int w = blockIdx.x * 4 + (threadIdx.x >> 6);
    if (w >= 8750) return;
    int g7 = w / 7, r7 = w - g7 * 7;
    if (r7 < 3)
        vfe_wave<CA, CA + 5, PA>(g7 * 3 + r7, vox_a, coor_a, np_a,
                                 w_a, b_a, feat_a, win, 0);
    else
        vfe_wave<CR, CR + 5, PR>(g7 * 4 + (r7 - 3), vox_r, coor_r, np_r,
                                 w_r, b_r, feat_r, win, 1);
}

// ---------------------------------------------------------------------------
// Conv v4 (unchanged): 4 channel-phases of 32, block = 4 rows x 64
// cells, 396-cell halo staged via winner map into LDS (80 B cell stride).
__global__ void __launch_bounds__(256) conv_kernel(
    const unsigned short* __restrict__ feat_a,
    const unsigned short* __restrict__ feat_r,
    const int2* __restrict__ win2,            // {agent, rg} per cell
    const unsigned short* __restrict__ bpack,
    const float* __restrict__ conv_b,
    float* __restrict__ out)
{
    __shared__ uint4 sA[396 * 5];             // 31,680 B (5th uint4 = pad)

    int tid  = threadIdx.x;
    int lane = tid & 63;
    int wv   = tid >> 6;
    int bid  = blockIdx.x;
    int xg = bid & 3, yg = (bid >> 2) & 63, b = bid >> 8;
    int x0 = xg * 64, y0 = yg * 4;
    int mrow = lane & 15, quad = lane >> 4;

    // winner indices for this thread's (up to) 2 halo cells — loaded ONCE
    int wA[2] = {-1, -1}, wR[2] = {-1, -1};
#pragma unroll
    for (int r = 0; r < 2; ++r) {
        int cell = tid + r * 256;
        if (cell < 396) {
            int iy = cell / 66, ix = cell - iy * 66;
            int yy = y0 - 1 + iy, xx = x0 - 1 + ix;
            if ((unsigned)yy < 256u && (unsigned)xx < 256u) {
                int2 w2 = win2[(((b << 8) + yy) << 8) + xx];
                wA[r] = w2.x; wR[r] = w2.y;
            }
        }
    }

    f32x4 acc0[4], acc1[4];
#pragma unroll
    for (int mt = 0; mt < 4; ++mt) {
        acc0[mt] = (f32x4){0.f, 0.f, 0.f, 0.f};
        acc1[mt] = (f32x4){0.f, 0.f, 0.f, 0.f};
    }

#pragma unroll
    for (int ph = 0; ph < 4; ++ph) {
        const unsigned short* feat = (ph < 2) ? feat_a : feat_r;
        const int half = (ph & 1) * 32;       // channel offset within feat row

        // ---- stage this phase's 32 channels for all 396 halo cells ----
#pragma unroll
        for (int r = 0; r < 2; ++r) {
            int cell = tid + r * 256;
            if (cell < 396) {
                int w = (ph < 2) ? wA[r] : wR[r];
                uint4* dst = &sA[cell * 5];
                if (w >= 0) {
                    const uint4* src = (const uint4*)(feat + ((long)w << 6) + half);
                    dst[0] = src[0]; dst[1] = src[1];
                    dst[2] = src[2]; dst[3] = src[3];
                } else {
                    uint4 zz = {0, 0, 0, 0};
                    dst[0] = zz; dst[1] = zz; dst[2] = zz; dst[3] = zz;
                }
            }
        }
        __syncthreads();

        // ---- compute: kk = ph, 9 taps x 4 Mtiles x 2 Ntiles ----
#pragma unroll
        for (int tap = 0; tap < 9; ++tap) {
            const int dyo = tap / 3, dxo = tap % 3;
            const unsigned short* bp = bpack + tap * 4096 + ph * 1024 + lane * 8;
            bf16x8 bn0 = *(const bf16x8*)(bp);
            bf16x8 bn1 = *(const bf16x8*)(bp + 512);
            int iy = wv + dyo;
#pragma unroll
            for (int mt = 0; mt < 4; ++mt) {
                int ix = mt * 16 + mrow + dxo;
                bf16x8 a = *(const bf16x8*)(&sA[(iy * 66 + ix) * 5 + quad]);
                acc0[mt] = __builtin_amdgcn_mfma_f32_16x16x32_bf16(a, bn0, acc0[mt], 0, 0, 0);
                acc1[mt] = __builtin_amdgcn_mfma_f32_16x16x32_bf16(a, bn1, acc1[mt], 0, 0, 0);
            }
        }
        __syncthreads();
    }

    // ---- Epilogue: D layout col=lane&15, row=quad*4+reg ----
    int col = lane & 15;
    float bias0 = conv_b[col];
    float bias1 = conv_b[col + 16];
    int cellbase = ((((b << 8) + y0 + wv)) << 8) + x0;
#pragma unroll
    for (int mt = 0; mt < 4; ++mt) {
#pragma unroll
        for (int r = 0; r < 4; ++r) {
            int cell = cellbase + mt * 16 + quad * 4 + r;
            float* o = out + (long)cell * 32;
            o[col]      = acc0[mt][r] + bias0;
            o[col + 16] = acc1[mt][r] + bias1;
        }
    }
}

// ---------------------------------------------------------------------------
extern "C" void kernel_launch(void* const* d_in, const int* in_sizes, int n_in,
                              void* d_out, int out_size, void* d_ws, size_t ws_size,
                              hipStream_t stream)
{
    const float* vox_a  = (const float*)d_in[0];
    const int*   coor_a = (const int*)d_in[1];
    const int*   np_a   = (const int*)d_in[2];
    const float* vox_r  = (const float*)d_in[3];
    const int*   coor_r = (const int*)d_in[4];
    const int*   np_r   = (const int*)d_in[5];
    const float* w_a    = (const float*)d_in[6];
    const float* b_a    = (const float*)d_in[7];
    const float* w_r    = (const float*)d_in[8];
    const float* b_r    = (const float*)d_in[9];
    const float* conv_w = (const float*)d_in[10];
    const float* conv_b = (const float*)d_in[11];
    float* out = (float*)d_out;

    // Workspace layout (16B-aligned offsets), total ~22.2 MB
    char* ws = (char*)d_ws;
    unsigned short* feat_a = (unsigned short*)(ws);                          // 7,680,000 B
    unsigned short* feat_r = (unsigned short*)(ws + 7680000);                // 10,240,000 B
    int* win               = (int*)(ws + 17920000);                          // 4,194,304 B (int2/cell)
    unsigned short* bpack  = (unsigned short*)(ws + 17920000 + 4194304);     // 73,728 B

    // 1a) winner map = -1 via DMA memset (0xFF bytes == -1 int), capture-safe
    hipMemsetAsync(win, 0xFF, 2 * (size_t)NCELL * sizeof(int), stream);
    // 1b) prep: weight pack only (144 blocks)
    hipLaunchKernelGGL(prep_kernel, dim3(144), dim3(256), 0, stream,
                       conv_w, bpack);
    // 2) unified VFE: 8750 waves = 2188 blocks x 4 waves, agent:rg 3:4
    hipLaunchKernelGGL(vfe_all, dim3((8750 + 3) / 4), dim3(256), 0, stream,
                       vox_a, coor_a, np_a, w_a, b_a, feat_a,
                       vox_r, coor_r, np_r, w_r, b_r, feat_r, win);
    // 3) conv v4: block = 4 rows x 64 cells, 4 channel-phases
    hipLaunchKernelGGL(conv_kernel, dim3(2048), dim3(256), 0, stream,
                       feat_a, feat_r, (const int2*)win, bpack, conv_b, out);
}

// Round 7
// 221.283 us; speedup vs baseline: 1.1843x; 1.1843x over previous
//
#include <hip/hip_runtime.h>
#include <hip/hip_bf16.h>

// Problem constants (from reference)
#define MA 60000
#define PA 20
#define CA 5
#define MR 80000
#define PR 32
#define CR 3
#define NXg 256
#define NYg 256
#define NB 8
#define NCELL (NB * NYg * NXg)   // 524288

typedef __bf16 bf16x8 __attribute__((ext_vector_type(8)));
typedef float  f32x4  __attribute__((ext_vector_type(4)));
typedef float  f4     __attribute__((ext_vector_type(4)));
typedef float  f2     __attribute__((ext_vector_type(2)));

__device__ __forceinline__ unsigned short f2bf(float f) {
    unsigned int u = __float_as_uint(f);
    u += 0x7fffu + ((u >> 16) & 1u);   // round-to-nearest-even
    return (unsigned short)(u >> 16);
}

// ---------------------------------------------------------------------------
// prep: conv-weight B-fragment pack only (win init via hipMemsetAsync).
// Pack order: offset = tap*4096 + kk*1024 + nt*512 + lane*8 + j,
// with n = nt*16+(lane&15), k = kk*32+(lane>>4)*8+j.
__global__ void __launch_bounds__(256) prep_kernel(const float* __restrict__ conv_w,
                                                   unsigned short* __restrict__ bp) {
    int i = blockIdx.x * 256 + threadIdx.x;    // < 144*256 = 36864 exactly
    int j    = i & 7;
    int lane = (i >> 3) & 63;
    int nt   = (i >> 9) & 1;
    int kk   = (i >> 10) & 3;
    int tap  = i >> 12;
    int n = nt * 16 + (lane & 15);
    int k = kk * 32 + (lane >> 4) * 8 + j;
    bp[i] = f2bf(conv_w[(tap * 128 + k) * 32 + n]);
}

// ---------------------------------------------------------------------------
// Pillar VFE v12: v10 (barrier-free wave-private LDS) + conflict-free pad +
// 2-stage ds_read pipeline.
//  - pillar LDS stride SRP=112 floats (448 B): lane-stride = 16 banks mod 32
//    -> 2-way access (free), fixes v10's 32-way rg dup/mean conflicts.
//  - compute loop double-buffers groups in registers (vA/vB, static indexing)
//    so the next group's ds_read issues before the current group's math.
//  - staging skips fully-invalid chunks; dup-fill + per-pillar mean by lane
//    pi; mean broadcast via tiny LDS f4 array (uniform read = broadcast).
template <int CIN, int CF, int PMAX, int PMAXp>
__device__ __forceinline__ void vfe_wave(
    int wpid, const float* __restrict__ vox, const int* __restrict__ coors,
    const int* __restrict__ npts, const float* __restrict__ W,
    const float* __restrict__ bias, unsigned short* __restrict__ feat,
    int* __restrict__ win, int which, float* __restrict__ ws)
{
    constexpr int SRP   = 112;             // padded pillar stride (floats)
    constexpr int PP4   = PMAXp / 4;       // f4s per channel row
    constexpr int CPP   = PMAX / 4;        // 4-point chunks per pillar
    constexpr int NCH   = 16 * CPP;        // chunks per wave (80 / 128)
    constexpr int CITER = (NCH + 63) / 64; // 2 for both
    constexpr int MEANF = 16 * SRP;        // float offset of mean array

    int lane = threadIdx.x & 63;
    int base = wpid * 16;                  // 16 pillars/wave, exact fit

    f4* mean4 = (f4*)(ws + MEANF);

    // ---- per-lane weight column + folded weights ----
    float wc[CF];
#pragma unroll
    for (int c = 0; c < CF; ++c) wc[c] = W[c * 64 + lane];
    float bd = bias[lane];
    f2 we2[CIN];
    we2[0] = (f2){wc[0] + wc[CIN + 0] + wc[CIN + 3], wc[0] + wc[CIN + 0] + wc[CIN + 3]};
    we2[1] = (f2){wc[1] + wc[CIN + 1] + wc[CIN + 4], wc[1] + wc[CIN + 1] + wc[CIN + 4]};
    we2[2] = (f2){wc[2] + wc[CIN + 2], wc[2] + wc[CIN + 2]};
#pragma unroll
    for (int c = 3; c < CIN; ++c) we2[c] = (f2){wc[c], wc[c]};

    // ---- staging: one lane per 4-point chunk; skip fully-invalid chunks ----
    {
        const f4* gv = (const f4*)vox + (size_t)base * (CPP * CIN);
#pragma unroll
        for (int it = 0; it < CITER; ++it) {
            int c0 = it * 64 + lane;
            if (c0 < NCH) {
                int p = c0 / CPP;              // compile-time-const divisor
                int g = c0 - p * CPP;
                int npc = npts[base + p];
                npc = npc < 1 ? 1 : (npc > PMAX ? PMAX : npc);
                if (g * 4 < npc) {             // chunk has >=1 valid point
                    const f4* src = gv + c0 * CIN;
                    f4 q[CIN];
#pragma unroll
                    for (int t = 0; t < CIN; ++t) q[t] = src[t];
                    float* dst = ws + p * SRP + g * 4;
#pragma unroll
                    for (int cch = 0; cch < CIN; ++cch) {
                        f4 w;
#pragma unroll
                        for (int j = 0; j < 4; ++j) {
                            int e = j * CIN + cch;     // compile-time
                            w[j] = q[e >> 2][e & 3];
                        }
                        *(f4*)(dst + cch * PMAXp) = w; // 16B-aligned always
                    }
                }
            }
        }
    }

    // ---- dup-fill + per-pillar mean (one lane per pillar; same-wave LDS
    //      program order guarantees staging writes are visible) ----
    if (lane < 16) {
        int np = npts[base + lane];
        np = np < 1 ? 1 : (np > PMAX ? PMAX : np);
        int np4 = (np + 3) & ~3;
        int nblk = np4 >> 2;
        float* pb = ws + lane * SRP;       // lane stride 448B -> 2-way banks
        float v0[CIN];
#pragma unroll
        for (int c = 0; c < CIN; ++c) v0[c] = pb[c * PMAXp];
        for (int p = np; p < np4; ++p)
#pragma unroll
            for (int c = 0; c < CIN; ++c) pb[c * PMAXp + p] = v0[c];
        const f4* pb4 = (const f4*)pb;
        f4 ax = {0.f,0.f,0.f,0.f}, ay = {0.f,0.f,0.f,0.f}, az = {0.f,0.f,0.f,0.f};
        for (int g = 0; g < nblk; ++g) {
            ax += pb4[0 * PP4 + g];
            ay += pb4[1 * PP4 + g];
            az += pb4[2 * PP4 + g];
        }
        float kf = (float)(np4 - np);
        float sx = (ax[0] + ax[1]) + (ax[2] + ax[3]) - kf * v0[0];
        float sy = (ay[0] + ay[1]) + (ay[2] + ay[3]) - kf * v0[1];
        float sz = (az[0] + az[1]) + (az[2] + az[3]) - kf * v0[2];
        float inv = 1.0f / (float)np;
        mean4[lane] = (f4){sx * inv, sy * inv, sz * inv, 0.0f};
    }

    // ---- meta prefetch (wave-uniform scalar loads) ----
    int np_n = npts[base];
    int cb_n = coors[base * 3 + 0];
    int cy_n = coors[base * 3 + 1];
    int cx_n = coors[base * 3 + 2];

    // ---- compute: 16 serial pillars, 2-stage pipelined group reads ----
    for (int pi = 0; pi < 16; ++pi) {
        int np = np_n, cb = cb_n, cy = cy_n, cx = cx_n;
        int pn = pi + 1;
        if (pn < 16) {
            np_n = npts[base + pn];
            cb_n = coors[(base + pn) * 3 + 0];
            cy_n = coors[(base + pn) * 3 + 1];
            cx_n = coors[(base + pn) * 3 + 2];
        }
        np = np < 1 ? 1 : (np > PMAX ? PMAX : np);
        int nblk = (np + 3) >> 2;

        const f4* pf4 = (const f4*)(ws + pi * SRP);
        f4 m4 = mean4[pi];                 // wave-uniform broadcast read
        f2 b2 = {-1e30f, -1e30f};

        f4 vA[CIN], vB[CIN];
#pragma unroll
        for (int c = 0; c < CIN; ++c) vA[c] = pf4[c * PP4];   // group 0

        for (int g = 0; g < nblk; g += 2) {
            bool hb = (g + 1 < nblk);
            if (hb) {
#pragma unroll
                for (int c = 0; c < CIN; ++c) vB[c] = pf4[c * PP4 + g + 1];
            }
            // compute group A (reads issued an iteration ahead)
#pragma unroll
            for (int j = 0; j < 2; ++j) {
                f2 d2 = (f2){vA[0][2*j], vA[0][2*j+1]} * we2[0]
                      + (f2){vA[1][2*j], vA[1][2*j+1]} * we2[1]
                      + (f2){vA[2][2*j], vA[2][2*j+1]} * we2[2];
#pragma unroll
                for (int c = 3; c < CIN; ++c)
                    d2 += (f2){vA[c][2*j], vA[c][2*j+1]} * we2[c];
                b2 = __builtin_elementwise_max(b2, d2);
            }
            if (g + 2 < nblk) {
#pragma unroll
                for (int c = 0; c < CIN; ++c) vA[c] = pf4[c * PP4 + g + 2];
            }
            if (hb) {
#pragma unroll
                for (int j = 0; j < 2; ++j) {
                    f2 d2 = (f2){vB[0][2*j], vB[0][2*j+1]} * we2[0]
                          + (f2){vB[1][2*j], vB[1][2*j+1]} * we2[1]
                          + (f2){vB[2][2*j], vB[2][2*j+1]} * we2[2];
#pragma unroll
                    for (int c = 3; c < CIN; ++c)
                        d2 += (f2){vB[c][2*j], vB[c][2*j+1]} * we2[c];
                    b2 = __builtin_elementwise_max(b2, d2);
                }
            }
        }

        float sbest = fmaxf(b2[0], b2[1]);
        float xo = (float)cx * 0.3125f + (-39.84375f);   // VX, X_OFF exact
        float yo = (float)cy * 0.3125f + (-19.84375f);
        float off = bd - (m4[0] * wc[CIN + 0] + m4[1] * wc[CIN + 1] + m4[2] * wc[CIN + 2])
                       - xo * wc[CIN + 3] - yo * wc[CIN + 4];
        float best = fmaxf(0.0f, sbest + off);

        feat[(size_t)(base + pi) * 64 + lane] = f2bf(best);

        if (lane == 0) {
            // numpy last-write-wins == max pillar index wins; int2 map
            atomicMax(&win[((cb * NYg + cy) * NXg + cx) * 2 + which], base + pi);
        }
    }
}

// Unified VFE launch: 8750 waves (3750 agent + 5000 rg), 4 waves/block,
// interleaved 3:4 (3750:5000 = 3:4 exactly). No __syncthreads anywhere.
// LDS: 4 x 1856 floats = 29696 B -> 5 blocks/CU (20 waves, 62.5% cap).
__global__ void __launch_bounds__(256, 5) vfe_all(
    const float* __restrict__ vox_a, const int* __restrict__ coor_a,
    const int* __restrict__ np_a, const float* __restrict__ w_a,
    const float* __restrict__ b_a, unsigned short* __restrict__ feat_a,
    const float* __restrict__ vox_r, const int* __restrict__ coor_r,
    const int* __restrict__ np_r, const float* __restrict__ w_r,
    const float* __restrict__ b_r, unsigned short* __restrict__ feat_r,
    int* __restrict__ win)
{
    constexpr int WSLOT = 16 * 112 + 64;   // 1856 floats per wave
    __shared__ __align__(16) float smem[4 * WSLOT];   // 29696 B
    int wv = threadIdx.x >> 6;
    int w  = blockIdx.x * 4 + wv;
    if (w >= 8750) return;
    int g7 = w / 7, r7 = w - g7 * 7;
    float* ws = smem + wv * WSLOT;
    if (r7 < 3)
        vfe_wave<CA, CA + 5, PA, 20>(g7 * 3 + r7, vox_a, coor_a, np_a,
                                     w_a, b_a, feat_a, win, 0, ws);
    else
        vfe_wave<CR, CR + 5, PR, 32>(g7 * 4 + (r7 - 3), vox_r, coor_r, np_r,
                                     w_r, b_r, feat_r, win, 1, ws);
}

// ---------------------------------------------------------------------------
// Conv v4 (unchanged): 4 channel-phases of 32, block = 4 rows x 64
// cells, 396-cell halo staged via winner map into LDS (80 B cell stride).
__global__ void __launch_bounds__(256) conv_kernel(
    const unsigned short* __restrict__ feat_a,
    const unsigned short* __restrict__ feat_r,
    const int2* __restrict__ win2,            // {agent, rg} per cell
    const unsigned short* __restrict__ bpack,
    const float* __restrict__ conv_b,
    float* __restrict__ out)
{
    __shared__ uint4 sA[396 * 5];             // 31,680 B (5th uint4 = pad)

    int tid  = threadIdx.x;
    int lane = tid & 63;
    int wv   = tid >> 6;
    int bid  = blockIdx.x;
    int xg = bid & 3, yg = (bid >> 2) & 63, b = bid >> 8;
    int x0 = xg * 64, y0 = yg * 4;
    int mrow = lane & 15, quad = lane >> 4;

    // winner indices for this thread's (up to) 2 halo cells — loaded ONCE
    int wA[2] = {-1, -1}, wR[2] = {-1, -1};
#pragma unroll
    for (int r = 0; r < 2; ++r) {
        int cell = tid + r * 256;
        if (cell < 396) {
            int iy = cell / 66, ix = cell - iy * 66;
            int yy = y0 - 1 + iy, xx = x0 - 1 + ix;
            if ((unsigned)yy < 256u && (unsigned)xx < 256u) {
                int2 w2 = win2[(((b << 8) + yy) << 8) + xx];
                wA[r] = w2.x; wR[r] = w2.y;
            }
        }
    }

    f32x4 acc0[4], acc1[4];
#pragma unroll
    for (int mt = 0; mt < 4; ++mt) {
        acc0[mt] = (f32x4){0.f, 0.f, 0.f, 0.f};
        acc1[mt] = (f32x4){0.f, 0.f, 0.f, 0.f};
    }

#pragma unroll
    for (int ph = 0; ph < 4; ++ph) {
        const unsigned short* feat = (ph < 2) ? feat_a : feat_r;
        const int half = (ph & 1) * 32;       // channel offset within feat row

        // ---- stage this phase's 32 channels for all 396 halo cells ----
#pragma unroll
        for (int r = 0; r < 2; ++r) {
            int cell = tid + r * 256;
            if (cell < 396) {
                int w = (ph < 2) ? wA[r] : wR[r];
                uint4* dst = &sA[cell * 5];
                if (w >= 0) {
                    const uint4* src = (const uint4*)(feat + ((long)w << 6) + half);
                    dst[0] = src[0]; dst[1] = src[1];
                    dst[2] = src[2]; dst[3] = src[3];
                } else {
                    uint4 zz = {0, 0, 0, 0};
                    dst[0] = zz; dst[1] = zz; dst[2] = zz; dst[3] = zz;
                }
            }
        }
        __syncthreads();

        // ---- compute: kk = ph, 9 taps x 4 Mtiles x 2 Ntiles ----
#pragma unroll
        for (int tap = 0; tap < 9; ++tap) {
            const int dyo = tap / 3, dxo = tap % 3;
            const unsigned short* bp = bpack + tap * 4096 + ph * 1024 + lane * 8;
            bf16x8 bn0 = *(const bf16x8*)(bp);
            bf16x8 bn1 = *(const bf16x8*)(bp + 512);
            int iy = wv + dyo;
#pragma unroll
            for (int mt = 0; mt < 4; ++mt) {
                int ix = mt * 16 + mrow + dxo;
                bf16x8 a = *(const bf16x8*)(&sA[(iy * 66 + ix) * 5 + quad]);
                acc0[mt] = __builtin_amdgcn_mfma_f32_16x16x32_bf16(a, bn0, acc0[mt], 0, 0, 0);
                acc1[mt] = __builtin_amdgcn_mfma_f32_16x16x32_bf16(a, bn1, acc1[mt], 0, 0, 0);
            }
        }
        __syncthreads();
    }

    // ---- Epilogue: D layout col=lane&15, row=quad*4+reg ----
    int col = lane & 15;
    float bias0 = conv_b[col];
    float bias1 = conv_b[col + 16];
    int cellbase = ((((b << 8) + y0 + wv)) << 8) + x0;
#pragma unroll
    for (int mt = 0; mt < 4; ++mt) {
#pragma unroll
        for (int r = 0; r < 4; ++r) {
            int cell = cellbase + mt * 16 + quad * 4 + r;
            float* o = out + (long)cell * 32;
            o[col]      = acc0[mt][r] + bias0;
            o[col + 16] = acc1[mt][r] + bias1;
        }
    }
}

// ---------------------------------------------------------------------------
extern "C" void kernel_launch(void* const* d_in, const int* in_sizes, int n_in,
                              void* d_out, int out_size, void* d_ws, size_t ws_size,
                              hipStream_t stream)
{
    const float* vox_a  = (const float*)d_in[0];
    const int*   coor_a = (const int*)d_in[1];
    const int*   np_a   = (const int*)d_in[2];
    const float* vox_r  = (const float*)d_in[3];
    const int*   coor_r = (const int*)d_in[4];
    const int*   np_r   = (const int*)d_in[5];
    const float* w_a    = (const float*)d_in[6];
    const float* b_a    = (const float*)d_in[7];
    const float* w_r    = (const float*)d_in[8];
    const float* b_r    = (const float*)d_in[9];
    const float* conv_w = (const float*)d_in[10];
    const float* conv_b = (const float*)d_in[11];
    float* out = (float*)d_out;

    // Workspace layout (16B-aligned offsets), total ~22.2 MB
    char* ws = (char*)d_ws;
    unsigned short* feat_a = (unsigned short*)(ws);                          // 7,680,000 B
    unsigned short* feat_r = (unsigned short*)(ws + 7680000);                // 10,240,000 B
    int* win               = (int*)(ws + 17920000);                          // 4,194,304 B (int2/cell)
    unsigned short* bpack  = (unsigned short*)(ws + 17920000 + 4194304);     // 73,728 B

    // 1a) winner map = -1 via DMA memset (0xFF bytes == -1 int), capture-safe
    hipMemsetAsync(win, 0xFF, 2 * (size_t)NCELL * sizeof(int), stream);
    // 1b) prep: weight pack only (144 blocks)
    hipLaunchKernelGGL(prep_kernel, dim3(144), dim3(256), 0, stream,
                       conv_w, bpack);
    // 2) unified VFE: 8750 waves = 2188 blocks x 4 waves, agent:rg 3:4
    hipLaunchKernelGGL(vfe_all, dim3((8750 + 3) / 4), dim3(256), 0, stream,
                       vox_a, coor_a, np_a, w_a, b_a, feat_a,
                       vox_r, coor_r, np_r, w_r, b_r, feat_r, win);
    // 3) conv v4: block = 4 rows x 64 cells, 4 channel-phases
    hipLaunchKernelGGL(conv_kernel, dim3(2048), dim3(256), 0, stream,
                       feat_a, feat_r, (const int2*)win, bpack, conv_b, out);
}

// Round 8
// 184.156 us; speedup vs baseline: 1.4231x; 1.2016x over previous
//
#include <hip/hip_runtime.h>
#include <hip/hip_bf16.h>

// Problem constants (from reference)
#define MA 60000
#define PA 20
#define CA 5
#define MR 80000
#define PR 32
#define CR 3
#define NXg 256
#define NYg 256
#define NB 8
#define NCELL (NB * NYg * NXg)   // 524288

typedef __bf16 bf16x8 __attribute__((ext_vector_type(8)));
typedef float  f32x4  __attribute__((ext_vector_type(4)));
typedef float  f4     __attribute__((ext_vector_type(4)));
typedef float  f2     __attribute__((ext_vector_type(2)));

__device__ __forceinline__ unsigned short f2bf(float f) {
    unsigned int u = __float_as_uint(f);
    u += 0x7fffu + ((u >> 16) & 1u);   // round-to-nearest-even
    return (unsigned short)(u >> 16);
}

// ---------------------------------------------------------------------------
// Pillar VFE v13: v10 structure (barrier-free wave-private LDS, no manual
// pipeline) with:
//  - 8 pillars/wave (17500 waves): shorter serial chains, 1-round staging,
//    finer tail; LDS 13.3 KB/block -> occupancy capped by waves (8 blk/CU).
//  - SRP=100 both dtypes (stride = 4 mod 32 banks): dup/mean section is
//    2 lanes/bank = conflict-free (v10's rg stride 96 = 0 mod 32 = 16-way).
//  - weight-pack folded into this kernel's blocks [0,144) (one less launch).
template <int CIN, int CF, int PMAX, int PMAXp>
__device__ __forceinline__ void vfe_wave(
    int wpid, const float* __restrict__ vox, const int* __restrict__ coors,
    const int* __restrict__ npts, const float* __restrict__ W,
    const float* __restrict__ bias, unsigned short* __restrict__ feat,
    int* __restrict__ win, int which, float* __restrict__ ws)
{
    constexpr int SRP   = 100;             // pillar stride (floats), 4 mod 32
    constexpr int PP4   = PMAXp / 4;       // f4s per channel row
    constexpr int CPP   = PMAX / 4;        // 4-point chunks per pillar
    constexpr int NCH   = 8 * CPP;         // chunks per wave (40 / 64)
    constexpr int MEANF = 8 * SRP;         // float offset of mean array

    int lane = threadIdx.x & 63;
    int base = wpid * 8;                   // 8 pillars/wave, exact fit

    f4* mean4 = (f4*)(ws + MEANF);

    // ---- per-lane weight column + folded weights ----
    float wc[CF];
#pragma unroll
    for (int c = 0; c < CF; ++c) wc[c] = W[c * 64 + lane];
    float bd = bias[lane];
    f2 we2[CIN];
    we2[0] = (f2){wc[0] + wc[CIN + 0] + wc[CIN + 3], wc[0] + wc[CIN + 0] + wc[CIN + 3]};
    we2[1] = (f2){wc[1] + wc[CIN + 1] + wc[CIN + 4], wc[1] + wc[CIN + 1] + wc[CIN + 4]};
    we2[2] = (f2){wc[2] + wc[CIN + 2], wc[2] + wc[CIN + 2]};
#pragma unroll
    for (int c = 3; c < CIN; ++c) we2[c] = (f2){wc[c], wc[c]};

    // ---- staging: one lane per 4-point chunk (single round); skip
    //      fully-invalid chunks (g*4 >= np) ----
    if (lane < NCH) {
        int p = lane / CPP;                // compile-time-const divisor
        int g = lane - p * CPP;
        int npc = npts[base + p];
        npc = npc < 1 ? 1 : (npc > PMAX ? PMAX : npc);
        if (g * 4 < npc) {                 // chunk has >=1 valid point
            const f4* src = (const f4*)vox + ((size_t)base * CPP + lane) * CIN;
            f4 q[CIN];
#pragma unroll
            for (int t = 0; t < CIN; ++t) q[t] = src[t];
            float* dst = ws + p * SRP + g * 4;
#pragma unroll
            for (int cch = 0; cch < CIN; ++cch) {
                f4 w;
#pragma unroll
                for (int j = 0; j < 4; ++j) {
                    int e = j * CIN + cch;         // compile-time after unroll
                    w[j] = q[e >> 2][e & 3];
                }
                *(f4*)(dst + cch * PMAXp) = w;     // 16B-aligned always
            }
        }
    }

    // ---- dup-fill + per-pillar mean (one lane per pillar; same-wave LDS
    //      program order makes staging writes visible). Lane stride 400 B
    //      = bank 4 mod 32 -> 2 lanes/bank (free). ----
    if (lane < 8) {
        int np = npts[base + lane];
        np = np < 1 ? 1 : (np > PMAX ? PMAX : np);
        int np4 = (np + 3) & ~3;
        int nblk = np4 >> 2;
        float* pb = ws + lane * SRP;
        float v0[CIN];
#pragma unroll
        for (int c = 0; c < CIN; ++c) v0[c] = pb[c * PMAXp];
        for (int p = np; p < np4; ++p)
#pragma unroll
            for (int c = 0; c < CIN; ++c) pb[c * PMAXp + p] = v0[c];
        const f4* pb4 = (const f4*)pb;
        f4 ax = {0.f,0.f,0.f,0.f}, ay = {0.f,0.f,0.f,0.f}, az = {0.f,0.f,0.f,0.f};
        for (int g = 0; g < nblk; ++g) {
            ax += pb4[0 * PP4 + g];
            ay += pb4[1 * PP4 + g];
            az += pb4[2 * PP4 + g];
        }
        float kf = (float)(np4 - np);
        float sx = (ax[0] + ax[1]) + (ax[2] + ax[3]) - kf * v0[0];
        float sy = (ay[0] + ay[1]) + (ay[2] + ay[3]) - kf * v0[1];
        float sz = (az[0] + az[1]) + (az[2] + az[3]) - kf * v0[2];
        float inv = 1.0f / (float)np;
        mean4[lane] = (f4){sx * inv, sy * inv, sz * inv, 0.0f};
    }

    // ---- meta prefetch (wave-uniform scalar loads) ----
    int np_n = npts[base];
    int cb_n = coors[base * 3 + 0];
    int cy_n = coors[base * 3 + 1];
    int cx_n = coors[base * 3 + 2];

    // ---- compute: 8 serial pillars, dot+max only (v10 form) ----
    for (int pi = 0; pi < 8; ++pi) {
        int np = np_n, cb = cb_n, cy = cy_n, cx = cx_n;
        int pn = pi + 1;
        if (pn < 8) {
            np_n = npts[base + pn];
            cb_n = coors[(base + pn) * 3 + 0];
            cy_n = coors[(base + pn) * 3 + 1];
            cx_n = coors[(base + pn) * 3 + 2];
        }
        np = np < 1 ? 1 : (np > PMAX ? PMAX : np);
        int nblk = (np + 3) >> 2;

        const f4* pf4 = (const f4*)(ws + pi * SRP);
        f4 m4 = mean4[pi];                 // wave-uniform broadcast read
        f2 b2 = {-1e30f, -1e30f};

        for (int g = 0; g < nblk; ++g) {   // 4 points per group
            f4 v[CIN];
#pragma unroll
            for (int c = 0; c < CIN; ++c) v[c] = pf4[c * PP4 + g];
#pragma unroll
            for (int j = 0; j < 2; ++j) {  // point pair within group
                f2 d2 = (f2){v[0][2*j], v[0][2*j+1]} * we2[0]
                      + (f2){v[1][2*j], v[1][2*j+1]} * we2[1]
                      + (f2){v[2][2*j], v[2][2*j+1]} * we2[2];
#pragma unroll
                for (int c = 3; c < CIN; ++c)
                    d2 += (f2){v[c][2*j], v[c][2*j+1]} * we2[c];
                b2 = __builtin_elementwise_max(b2, d2);
            }
        }

        float sbest = fmaxf(b2[0], b2[1]);
        float xo = (float)cx * 0.3125f + (-39.84375f);   // VX, X_OFF exact
        float yo = (float)cy * 0.3125f + (-19.84375f);
        float off = bd - (m4[0] * wc[CIN + 0] + m4[1] * wc[CIN + 1] + m4[2] * wc[CIN + 2])
                       - xo * wc[CIN + 3] - yo * wc[CIN + 4];
        float best = fmaxf(0.0f, sbest + off);

        feat[(size_t)(base + pi) * 64 + lane] = f2bf(best);

        if (lane == 0) {
            // numpy last-write-wins == max pillar index wins; int2 map
            atomicMax(&win[((cb * NYg + cy) * NXg + cx) * 2 + which], base + pi);
        }
    }
}

// Unified VFE + weight-pack launch:
//   blocks [0, 144)       : conv-weight B-fragment pack (36864 items)
//   blocks [144, 144+4375): 17500 VFE waves (7500 agent + 10000 rg), 4/block,
//                           interleaved 3:4 (7500:10000 = 3:4 exactly).
// No __syncthreads anywhere. LDS 4 x 832 floats = 13312 B -> wave-capped
// occupancy (8 blocks/CU = 32 waves).
__global__ void __launch_bounds__(256, 6) vfe_all(
    const float* __restrict__ vox_a, const int* __restrict__ coor_a,
    const int* __restrict__ np_a, const float* __restrict__ w_a,
    const float* __restrict__ b_a, unsigned short* __restrict__ feat_a,
    const float* __restrict__ vox_r, const int* __restrict__ coor_r,
    const int* __restrict__ np_r, const float* __restrict__ w_r,
    const float* __restrict__ b_r, unsigned short* __restrict__ feat_r,
    int* __restrict__ win,
    const float* __restrict__ conv_w, unsigned short* __restrict__ bpack)
{
    constexpr int WSLOT = 8 * 100 + 32;    // 832 floats per wave
    __shared__ __align__(16) float smem[4 * WSLOT];   // 13312 B
    int bid = blockIdx.x;
    if (bid < 144) {
        // conv-weight pack: offset = tap*4096 + kk*1024 + nt*512 + lane*8 + j
        int i = bid * 256 + threadIdx.x;   // < 36864 exactly
        int j    = i & 7;
        int lane = (i >> 3) & 63;
        int nt   = (i >> 9) & 1;
        int kk   = (i >> 10) & 3;
        int tap  = i >> 12;
        int n = nt * 16 + (lane & 15);
        int k = kk * 32 + (lane >> 4) * 8 + j;
        bpack[i] = f2bf(conv_w[(tap * 128 + k) * 32 + n]);
        return;
    }
    int wv = threadIdx.x >> 6;
    int w  = (bid - 144) * 4 + wv;         // 0..17499
    int g7 = w / 7, r7 = w - g7 * 7;
    float* ws = smem + wv * WSLOT;
    if (r7 < 3)
        vfe_wave<CA, CA + 5, PA, 20>(g7 * 3 + r7, vox_a, coor_a, np_a,
                                     w_a, b_a, feat_a, win, 0, ws);
    else
        vfe_wave<CR, CR + 5, PR, 32>(g7 * 4 + (r7 - 3), vox_r, coor_r, np_r,
                                     w_r, b_r, feat_r, win, 1, ws);
}

// ---------------------------------------------------------------------------
// Conv v4 (unchanged): 4 channel-phases of 32, block = 4 rows x 64
// cells, 396-cell halo staged via winner map into LDS (80 B cell stride).
__global__ void __launch_bounds__(256) conv_kernel(
    const unsigned short* __restrict__ feat_a,
    const unsigned short* __restrict__ feat_r,
    const int2* __restrict__ win2,            // {agent, rg} per cell
    const unsigned short* __restrict__ bpack,
    const float* __restrict__ conv_b,
    float* __restrict__ out)
{
    __shared__ uint4 sA[396 * 5];             // 31,680 B (5th uint4 = pad)

    int tid  = threadIdx.x;
    int lane = tid & 63;
    int wv   = tid >> 6;
    int bid  = blockIdx.x;
    int xg = bid & 3, yg = (bid >> 2) & 63, b = bid >> 8;
    int x0 = xg * 64, y0 = yg * 4;
    int mrow = lane & 15, quad = lane >> 4;

    // winner indices for this thread's (up to) 2 halo cells — loaded ONCE
    int wA[2] = {-1, -1}, wR[2] = {-1, -1};
#pragma unroll
    for (int r = 0; r < 2; ++r) {
        int cell = tid + r * 256;
        if (cell < 396) {
            int iy = cell / 66, ix = cell - iy * 66;
            int yy = y0 - 1 + iy, xx = x0 - 1 + ix;
            if ((unsigned)yy < 256u && (unsigned)xx < 256u) {
                int2 w2 = win2[(((b << 8) + yy) << 8) + xx];
                wA[r] = w2.x; wR[r] = w2.y;
            }
        }
    }

    f32x4 acc0[4], acc1[4];
#pragma unroll
    for (int mt = 0; mt < 4; ++mt) {
        acc0[mt] = (f32x4){0.f, 0.f, 0.f, 0.f};
        acc1[mt] = (f32x4){0.f, 0.f, 0.f, 0.f};
    }

#pragma unroll
    for (int ph = 0; ph < 4; ++ph) {
        const unsigned short* feat = (ph < 2) ? feat_a : feat_r;
        const int half = (ph & 1) * 32;       // channel offset within feat row

        // ---- stage this phase's 32 channels for all 396 halo cells ----
#pragma unroll
        for (int r = 0; r < 2; ++r) {
            int cell = tid + r * 256;
            if (cell < 396) {
                int w = (ph < 2) ? wA[r] : wR[r];
                uint4* dst = &sA[cell * 5];
                if (w >= 0) {
                    const uint4* src = (const uint4*)(feat + ((long)w << 6) + half);
                    dst[0] = src[0]; dst[1] = src[1];
                    dst[2] = src[2]; dst[3] = src[3];
                } else {
                    uint4 zz = {0, 0, 0, 0};
                    dst[0] = zz; dst[1] = zz; dst[2] = zz; dst[3] = zz;
                }
            }
        }
        __syncthreads();

        // ---- compute: kk = ph, 9 taps x 4 Mtiles x 2 Ntiles ----
#pragma unroll
        for (int tap = 0; tap < 9; ++tap) {
            const int dyo = tap / 3, dxo = tap % 3;
            const unsigned short* bp = bpack + tap * 4096 + ph * 1024 + lane * 8;
            bf16x8 bn0 = *(const bf16x8*)(bp);
            bf16x8 bn1 = *(const bf16x8*)(bp + 512);
            int iy = wv + dyo;
#pragma unroll
            for (int mt = 0; mt < 4; ++mt) {
                int ix = mt * 16 + mrow + dxo;
                bf16x8 a = *(const bf16x8*)(&sA[(iy * 66 + ix) * 5 + quad]);
                acc0[mt] = __builtin_amdgcn_mfma_f32_16x16x32_bf16(a, bn0, acc0[mt], 0, 0, 0);
                acc1[mt] = __builtin_amdgcn_mfma_f32_16x16x32_bf16(a, bn1, acc1[mt], 0, 0, 0);
            }
        }
        __syncthreads();
    }

    // ---- Epilogue: D layout col=lane&15, row=quad*4+reg ----
    int col = lane & 15;
    float bias0 = conv_b[col];
    float bias1 = conv_b[col + 16];
    int cellbase = ((((b << 8) + y0 + wv)) << 8) + x0;
#pragma unroll
    for (int mt = 0; mt < 4; ++mt) {
#pragma unroll
        for (int r = 0; r < 4; ++r) {
            int cell = cellbase + mt * 16 + quad * 4 + r;
            float* o = out + (long)cell * 32;
            o[col]      = acc0[mt][r] + bias0;
            o[col + 16] = acc1[mt][r] + bias1;
        }
    }
}

// ---------------------------------------------------------------------------
extern "C" void kernel_launch(void* const* d_in, const int* in_sizes, int n_in,
                              void* d_out, int out_size, void* d_ws, size_t ws_size,
                              hipStream_t stream)
{
    const float* vox_a  = (const float*)d_in[0];
    const int*   coor_a = (const int*)d_in[1];
    const int*   np_a   = (const int*)d_in[2];
    const float* vox_r  = (const float*)d_in[3];
    const int*   coor_r = (const int*)d_in[4];
    const int*   np_r   = (const int*)d_in[5];
    const float* w_a    = (const float*)d_in[6];
    const float* b_a    = (const float*)d_in[7];
    const float* w_r    = (const float*)d_in[8];
    const float* b_r    = (const float*)d_in[9];
    const float* conv_w = (const float*)d_in[10];
    const float* conv_b = (const float*)d_in[11];
    float* out = (float*)d_out;

    // Workspace layout (16B-aligned offsets), total ~22.2 MB
    char* ws = (char*)d_ws;
    unsigned short* feat_a = (unsigned short*)(ws);                          // 7,680,000 B
    unsigned short* feat_r = (unsigned short*)(ws + 7680000);                // 10,240,000 B
    int* win               = (int*)(ws + 17920000);                          // 4,194,304 B (int2/cell)
    unsigned short* bpack  = (unsigned short*)(ws + 17920000 + 4194304);     // 73,728 B

    // 1) winner map = -1 via DMA memset (0xFF bytes == -1 int), capture-safe
    hipMemsetAsync(win, 0xFF, 2 * (size_t)NCELL * sizeof(int), stream);
    // 2) unified VFE (+ weight pack in blocks [0,144)):
    //    144 pack blocks + 4375 VFE blocks (17500 waves, agent:rg 3:4)
    hipLaunchKernelGGL(vfe_all, dim3(144 + 4375), dim3(256), 0, stream,
                       vox_a, coor_a, np_a, w_a, b_a, feat_a,
                       vox_r, coor_r, np_r, w_r, b_r, feat_r, win,
                       conv_w, bpack);
    // 3) conv v4: block = 4 rows x 64 cells, 4 channel-phases
    hipLaunchKernelGGL(conv_kernel, dim3(2048), dim3(256), 0, stream,
                       feat_a, feat_r, (const int2*)win, bpack, conv_b, out);
}